// Round 17
// baseline (115.610 us; speedup 1.0000x reference)
//
#include <hip/hip_runtime.h>

#define NEARZERO 1e-5f
#define RLEN 15
#define LOG2E 1.4426950408889634f

struct __attribute__((packed, aligned(4))) F3 { float x, y, z; };
static __device__ __forceinline__ F3 ldo(const char* base, unsigned voff) {
    return *reinterpret_cast<const F3*>(base + voff);
}

struct Par { float FC, invFC, invLPFC, K1, K2, PERC, UZL, TT, CFMAX, nCFRC, nCWH, C; };

// prologue-only: snow+soil of t=0
__device__ __forceinline__ void ab_step(
    const F3& f, const F3& d3, const Par& pr,
    float& SP, float& MW, float& SM, float& SLZ,
    float cs, float& rxP, float& k0P)
{
    const float dT   = f.y - pr.TT;
    const float SNOW = (dT >= 0.0f) ? 0.0f : f.x;
    const float RAIN = f.x - SNOW;
    SP += SNOW;
    const float melt = __builtin_amdgcn_fmed3f(pr.CFMAX * dT, 0.0f, SP);
    MW += melt;  SP -= melt;
    const float refr = __builtin_amdgcn_fmed3f(pr.nCFRC * dT, 0.0f, MW);
    SP += refr;  MW -= refr;
    const float tosoil = fmaxf(fmaf(pr.nCWH, SP, MW), 0.0f);
    MW -= tosoil;
    const float sw = fminf(exp2f(fmaf(d3.x, 5.0f, 1.0f) * __log2f(SM * pr.invFC)), 1.0f);
    const float rt = RAIN + tosoil;
    const float rc = rt * sw;
    SM = fmaf(rt, 1.0f - sw, SM);
    const float ex = fmaxf(SM - pr.FC, 0.0f);
    SM = fminf(SM, pr.FC);
    const float ef = fminf(exp2f(fmaf(d3.z, 4.7f, 0.3f) * __log2f(SM * pr.invLPFC)), 1.0f);
    SM = fmaxf(fmaf(-f.z, ef, SM), NEARZERO);
    const float u  = fminf(SM * pr.invFC, 1.0f);
    const float cap = fmaf(-cs, u, cs);
    SM  = fmaxf(SM + cap, NEARZERO);
    SLZ = fmaxf(SLZ - cap, NEARZERO);
    rxP = rc + ex;
    k0P = fmaf(d3.y, 0.85f, 0.05f);
}

// fused iteration m: finish(m) [zones+FIR+store] skew-interleaved with ab(m+1).
template<int PH>
__device__ __forceinline__ void fused_iter(
    const F3 f, const F3 d3, const Par& pr,
    float& SP, float& MW, float& SM, float& SUZ, float& SLZ,
    float& rxP, float& k0P,
    float (&acc)[RLEN], const float (&w)[RLEN],
    float* outp)
{
    // trans #1: SM(m) ready at entry
    const float t1 = __log2f(SM * pr.invFC);
    // snow(m+1)
    const float dT   = f.y - pr.TT;
    const float SNOW = (dT >= 0.0f) ? 0.0f : f.x;
    const float RAIN = f.x - SNOW;
    SP += SNOW;
    const float melt = __builtin_amdgcn_fmed3f(pr.CFMAX * dT, 0.0f, SP);
    MW += melt;  SP -= melt;
    const float refr = __builtin_amdgcn_fmed3f(pr.nCFRC * dT, 0.0f, MW);
    SP += refr;  MW -= refr;
    const float tosoil = fmaxf(fmaf(pr.nCWH, SP, MW), 0.0f);
    MW -= tosoil;
    // finish(m) upper zone (SSA-folded)
    const float a  = SUZ + rxP;
    const float PERCv = fminf(a, pr.PERC);
    const float b  = a - PERCv;
    const float Q0 = k0P * fmaxf(b - pr.UZL, 0.0f);
    const float c  = b - Q0;
    const float Q1 = pr.K1 * c;
    SUZ = c - Q1;
    // trans #2
    const float sw = fminf(exp2f(fmaf(d3.x, 5.0f, 1.0f) * t1), 1.0f);
    const float rt = RAIN + tosoil;
    // finish(m) lower zone
    const float dz = SLZ + PERCv;
    const float Q2 = pr.K2 * dz;
    SLZ = dz - Q2;
    const float cs = pr.C * SLZ;
    const float Qs = (Q0 + Q1) + Q2;
    // soil mid (m+1)
    const float rc = rt * sw;
    SM = fmaf(rt, 1.0f - sw, SM);
    const float ex = fmaxf(SM - pr.FC, 0.0f);
    SM = fminf(SM, pr.FC);
    // trans #3 (hidden under FIR)
    const float t2 = __log2f(SM * pr.invLPFC);
    // FIR(m) + store (unguarded: OOB threads returned at kernel entry)
    const float qr = fmaf(w[0], Qs, acc[PH]);
    acc[PH] = 0.0f;
#pragma unroll
    for (int k = 1; k < RLEN; ++k) {
        const int j = (PH + k) % RLEN;           // compile-time
        acc[j] = fmaf(w[k], Qs, acc[j]);
    }
    __builtin_nontemporal_store(qr, outp);
    // trans #4 + soil tail (m+1)
    const float ef = fminf(exp2f(fmaf(d3.z, 4.7f, 0.3f) * t2), 1.0f);
    SM = fmaxf(fmaf(-f.z, ef, SM), NEARZERO);
    const float u  = fminf(SM * pr.invFC, 1.0f);
    const float cap = fmaf(-cs, u, cs);          // cs*(1-u), single fma
    SM  = fmaxf(SM + cap, NEARZERO);
    SLZ = fmaxf(SLZ - cap, NEARZERO);
    rxP = rc + ex;
    k0P = fmaf(d3.y, 0.85f, 0.05f);
}

// final step's zones+FIR head+store only
template<int PH>
__device__ __forceinline__ void finish_last(
    const Par& pr, float& SUZ, float& SLZ, float rxP, float k0P,
    float (&acc)[RLEN], const float (&w)[RLEN], float* outp)
{
    const float a  = SUZ + rxP;
    const float PERCv = fminf(a, pr.PERC);
    const float b  = a - PERCv;
    const float Q0 = k0P * fmaxf(b - pr.UZL, 0.0f);
    const float c  = b - Q0;
    const float Q1 = pr.K1 * c;
    const float dz = SLZ + PERCv;
    const float Q2 = pr.K2 * dz;
    const float Qs = (Q0 + Q1) + Q2;
    const float qr = fmaf(w[0], Qs, acc[PH]);
    __builtin_nontemporal_store(qr, outp);
}

__global__ __launch_bounds__(256, 1)
void hbv_kernel(const float* __restrict__ forcing,   // (365,G,3)
                const float* __restrict__ dynr,      // (365,G,3)
                const float* __restrict__ statr,     // (G,15)
                float* __restrict__ out,             // (365,G)
                int G)
{
    const int g = blockIdx.x * 256 + threadIdx.x;
    if (g >= G) return;                // exec permanently masked for OOB lanes:
                                       // no per-step guard, no clamps below.

    // ---- static parameters ----
    const float* sp = statr + (size_t)g * 15;
    Par pr;
    pr.FC    = fmaf(sp[0], 950.0f, 50.0f);
    pr.K1    = fmaf(sp[1], 0.49f, 0.01f);
    pr.K2    = fmaf(sp[2], 0.199f, 0.001f);
    const float parLP = fmaf(sp[3], 0.8f, 0.2f);
    pr.PERC  = sp[4] * 10.0f;
    pr.UZL   = sp[5] * 100.0f;
    pr.TT    = fmaf(sp[6], 5.0f, -2.5f);
    pr.CFMAX = fmaf(sp[7], 9.5f, 0.5f);
    pr.nCFRC = -(sp[8] * 0.1f) * pr.CFMAX;
    pr.nCWH  = -(sp[9] * 0.2f);
    pr.C     = sp[10];
    const float rout_a = sp[13] * 2.9f;
    const float rout_b = sp[14] * 6.5f;
    pr.invFC   = 1.0f / pr.FC;
    pr.invLPFC = 1.0f / (parLP * pr.FC);

    // ---- routing weights (Gamma(aa)*theta^aa cancels in normalization) ----
    const float aa    = fmaxf(rout_a, 0.0f) + 0.1f;
    const float theta = fmaxf(rout_b, 0.0f) + 0.5f;
    const float am1   = aa - 1.0f;
    const float nitl2 = -LOG2E / theta;
    float w[RLEN];
    float wsum = 0.0f;
#pragma unroll
    for (int k = 0; k < RLEN; ++k) {
        const float tk = (float)k + 0.5f;
        w[k] = exp2f(am1 * __log2f(tk) + tk * nitl2);
        wsum += w[k];
    }
    const float winv = 1.0f / wsum;
#pragma unroll
    for (int k = 0; k < RLEN; ++k) w[k] *= winv;

    // ---- state ----
    float SP_ = 0.001f, MW = 0.001f, SM = 0.001f, SUZ = 0.001f, SLZ = 0.001f;
    float acc[RLEN];
#pragma unroll
    for (int k = 0; k < RLEN; ++k) acc[k] = 0.0f;
    float rxP = 0.0f, k0P = 0.0f;

    // ---- uniform-base + 32-bit running voffsets ----
    const char* fbase = (const char*)forcing;
    const char* dbase = (const char*)dynr;
    char*       obase = (char*)out;
    const unsigned G12 = (unsigned)G * 12u;
    const unsigned G4  = (unsigned)G * 4u;
    unsigned vRun = (unsigned)g * 12u;             // row 0
    unsigned vO   = (unsigned)g * 4u;              // out row 0

    // ---- depth-3 register ring (3 | 15 -> slot = (m+1) % 3, constexpr) ----
    F3 bF[3], bD[3];
#pragma unroll
    for (int r = 0; r < 3; ++r) {
        bF[r] = ldo(fbase, vRun); bD[r] = ldo(dbase, vRun);
        vRun += G12;
    }                                               // vRun at row 3

    // ---- prologue: ab(0); restage row 3 -> slot 0 ----
    {
        const float cs0 = pr.C * SLZ;
        const F3 f_ = bF[0], d_ = bD[0];
        bF[0] = ldo(fbase, vRun); bD[0] = ldo(dbase, vRun);
        vRun += G12;
        __builtin_amdgcn_sched_barrier(0x7);        // pin VMEM; ALU may cross
        ab_step(f_, d_, pr, SP_, MW, SM, SLZ, cs0, rxP, k0P);
    }

    // Iter m: consume row m+1 (slot (m+1)%3), stage row m+4 into same slot,
    // run fused_iter<m%15> = finish(m) + ab(m+1).
#define ITER(MM, DOLOAD) do { \
    constexpr int PH_ = (MM) % RLEN; \
    constexpr int S_  = ((MM) + 1) % 3; \
    const F3 f_ = bF[S_], d_ = bD[S_]; \
    if (DOLOAD) { \
        bF[S_] = ldo(fbase, vRun); bD[S_] = ldo(dbase, vRun); \
        vRun += G12; \
    } \
    __builtin_amdgcn_sched_barrier(0x7); \
    fused_iter<PH_>(f_, d_, pr, SP_, MW, SM, SUZ, SLZ, rxP, k0P, acc, w, \
                    (float*)(obase + vO)); \
    vO += G4; \
} while (0)

    // ---- main: m = 0..359 (24 x 15); stages rows 4..363 ----
    for (int i = 0; i < 24; ++i) {
        ITER(0, true);  ITER(1, true);  ITER(2, true);  ITER(3, true);  ITER(4, true);
        ITER(5, true);  ITER(6, true);  ITER(7, true);  ITER(8, true);  ITER(9, true);
        ITER(10, true); ITER(11, true); ITER(12, true); ITER(13, true); ITER(14, true);
    }
    // ---- m=360: stages row 364 (last real) ----
    ITER(0, true);
    // ---- m=361..363: consume rows 362..364, no load ----
    ITER(1, false);
    ITER(2, false);
    ITER(3, false);
    // ---- final: finish(364), phase 364 % 15 = 4 ----
    finish_last<4>(pr, SUZ, SLZ, rxP, k0P, acc, w, (float*)(obase + vO));
#undef ITER
}

extern "C" void kernel_launch(void* const* d_in, const int* in_sizes, int n_in,
                              void* d_out, int out_size, void* d_ws, size_t ws_size,
                              hipStream_t stream) {
    const float* forcing = (const float*)d_in[0];
    const float* dynr    = (const float*)d_in[1];
    const float* statr   = (const float*)d_in[2];
    float* out = (float*)d_out;

    const int G = in_sizes[2] / 15;          // static_raw (G,15); T fixed at 365
    const int block = 256;
    const int grid  = (G + block - 1) / block;
    hbv_kernel<<<grid, block, 0, stream>>>(forcing, dynr, statr, out, G);
}